// Round 3
// baseline (979.453 us; speedup 1.0000x reference)
//
#include <hip/hip_runtime.h>
#include <stdint.h>

// NodeModel: edge MLP (Lin 128->64 + BN(batch stats) + SiLU) -> scatter_mean -> node MLP.
// Inputs/outputs are float32 (per reference dtypes); edge_index int32 on device.
// MFMA in bf16 (RNE conversion at LDS staging), f32 accumulate.
//
// Recompute design (workspace ~26 MB):
//   pass0: edge GEMM -> column sum/sumsq          (no h1 materialization)
//   pass1: edge GEMM again -> norm+SiLU -> atomic scatter to sums/cnt
//   pass2: node GEMM ([x | sums/cnt]) -> column sum/sumsq
//   pass3: node GEMM again -> norm+SiLU -> f32 out

#define EPS 1e-5f

using short8  = __attribute__((ext_vector_type(8))) short;
using floatx4 = __attribute__((ext_vector_type(4))) float;

__device__ __forceinline__ ushort f2bf(float f) {
  uint32_t u = __builtin_bit_cast(uint32_t, f);
  u += 0x7fffu + ((u >> 16) & 1u);   // RNE
  return (ushort)(u >> 16);
}
__device__ __forceinline__ float silu(float v) {
  return v / (1.0f + __expf(-v));
}
__device__ __forceinline__ void pack4(ushort* dst, float4 v) {
  uint2 p;
  p.x = (uint)f2bf(v.x) | ((uint)f2bf(v.y) << 16);
  p.y = (uint)f2bf(v.z) | ((uint)f2bf(v.w) << 16);
  *(uint2*)dst = p;
}

// MODE: 0 = edge stats, 1 = edge scatter, 2 = node stats, 3 = node out
template <int MODE>
__global__ __launch_bounds__(256) void fused_gemm(
    const float* __restrict__ x, const float* __restrict__ ea,
    const float* __restrict__ sums_in, const float* __restrict__ cnt,
    const int* __restrict__ rowidx, const int* __restrict__ colidx,
    const float* __restrict__ W, const float* __restrict__ bias,
    const float* __restrict__ scsh,
    float* __restrict__ ssum, float* __restrict__ ssq,
    float* __restrict__ sums_out, float* __restrict__ cnt_out,
    float* __restrict__ out,
    int nrows, int ntiles) {
  // pad 128->136 ushorts: b128 reads land 2-way bank aliased (free on CDNA4)
  __shared__ __align__(16) ushort Albs[64 * 136];
  __shared__ __align__(16) ushort Btl[64 * 136];
  __shared__ float wsum[4][64];
  __shared__ float wsq[4][64];
  __shared__ float biasl[64];
  __shared__ float scl[128];
  __shared__ int coltile[64];

  const int tid  = threadIdx.x;
  const int lane = tid & 63;
  const int wv   = tid >> 6;
  const int m    = lane & 15;
  const int quad = lane >> 4;

  // Stage W^T (bf16) into LDS once per block: Btl[n][k] = bf16(W[k*64+n])
  for (int i = tid; i < 64 * 128; i += 256) {
    const int n = i >> 7, k = i & 127;
    Btl[n * 136 + k] = f2bf(W[k * 64 + n]);
  }
  if (tid < 64) biasl[tid] = bias[tid];
  if (MODE == 1 || MODE == 3) {
    if (tid < 128) scl[tid] = scsh[tid];
  }
  if (MODE == 0 || MODE == 2) {
    wsum[wv][lane] = 0.f;
    wsq[wv][lane]  = 0.f;
  }

  for (int t = blockIdx.x; t < ntiles; t += gridDim.x) {
    __syncthreads();  // prior tile's LDS reads done; also covers pre-loop staging
    const int base = t * 64;
    // Stage A tile: 64 rows x 128 f32 cols -> bf16 in LDS. 16B (4-float) chunks:
    // 32 chunks/row * 64 rows = 2048.
    for (int i = tid; i < 2048; i += 256) {
      const int e  = i >> 5;
      const int c4 = (i & 31) << 2;   // f32 col 0..124
      const int grow = base + e;
      float4 v = make_float4(0.f, 0.f, 0.f, 0.f);
      if (grow < nrows) {
        if (MODE <= 1) {
          if (c4 < 64) {
            const int r = rowidx[grow];
            v = *(const float4*)(x + (size_t)r * 64 + c4);
          } else {
            v = *(const float4*)(ea + (size_t)grow * 64 + (c4 - 64));
          }
          if (MODE == 1 && c4 == 0) coltile[e] = colidx[grow];
        } else {
          if (c4 < 64) {
            v = *(const float4*)(x + (size_t)grow * 64 + c4);
          } else {
            const float inv = 1.0f / fmaxf(cnt[grow], 1.0f);
            v = *(const float4*)(sums_in + (size_t)grow * 64 + (c4 - 64));
            v.x *= inv; v.y *= inv; v.z *= inv; v.w *= inv;
          }
        }
      }
      pack4(&Albs[e * 136 + c4], v);
    }
    __syncthreads();

    floatx4 acc[4];
#pragma unroll
    for (int nt = 0; nt < 4; ++nt) acc[nt] = (floatx4){0.f, 0.f, 0.f, 0.f};
    const ushort* arow = &Albs[(wv * 16 + m) * 136];
#pragma unroll
    for (int kc = 0; kc < 4; ++kc) {
      const short8 af = *(const short8*)(arow + kc * 32 + quad * 8);
#pragma unroll
      for (int nt = 0; nt < 4; ++nt) {
        const short8 bfr = *(const short8*)(&Btl[(nt * 16 + m) * 136 + kc * 32 + quad * 8]);
        acc[nt] = __builtin_amdgcn_mfma_f32_16x16x32_bf16(af, bfr, acc[nt], 0, 0, 0);
      }
    }

    // Epilogue. C/D layout: col = lane&15 (+nt*16), row = quad*4 + reg (m89-verified)
    const int lr0 = wv * 16 + quad * 4;  // local row base within 64-row tile
#pragma unroll
    for (int nt = 0; nt < 4; ++nt) {
      const int c = nt * 16 + m;
      const float bb = biasl[c];
      if (MODE == 0 || MODE == 2) {
        float s = 0.f, q = 0.f;
#pragma unroll
        for (int r = 0; r < 4; ++r) {
          const int grow = base + lr0 + r;
          if (grow < nrows) {
            const float v = acc[nt][r] + bb;
            s += v;
            q += v * v;
          }
        }
        s += __shfl_xor(s, 16); s += __shfl_xor(s, 32);
        q += __shfl_xor(q, 16); q += __shfl_xor(q, 32);
        if (quad == 0) { wsum[wv][c] += s; wsq[wv][c] += q; }
      } else {
        const float sc = scl[c];
        const float sh = scl[64 + c];
#pragma unroll
        for (int r = 0; r < 4; ++r) {
          const int e = lr0 + r;
          const int grow = base + e;
          if (grow < nrows) {
            const float o = silu((acc[nt][r] + bb) * sc + sh);
            if (MODE == 1) {
              unsafeAtomicAdd(&sums_out[(size_t)coltile[e] * 64 + c], o);
            } else {
              out[(size_t)grow * 64 + c] = o;
            }
          }
        }
        if (MODE == 1 && nt == 0 && m == 0) {
#pragma unroll
          for (int r = 0; r < 4; ++r) {
            const int e = lr0 + r;
            if (base + e < nrows) unsafeAtomicAdd(&cnt_out[coltile[e]], 1.0f);
          }
        }
      }
    }
  }

  if (MODE == 0 || MODE == 2) {
    __syncthreads();
    if (tid < 128) {
      const int c = tid & 63;
      if (tid < 64) {
        unsafeAtomicAdd(&ssum[c], wsum[0][c] + wsum[1][c] + wsum[2][c] + wsum[3][c]);
      } else {
        unsafeAtomicAdd(&ssq[c], wsq[0][c] + wsq[1][c] + wsq[2][c] + wsq[3][c]);
      }
    }
  }
}

__global__ void finalize_stats(const float* __restrict__ ss, const float* __restrict__ sq,
                               const float* __restrict__ g, const float* __restrict__ be,
                               float* __restrict__ scsh, float invn) {
  const int c = threadIdx.x;  // 64 threads
  const float mu  = ss[c] * invn;
  const float var = sq[c] * invn - mu * mu;
  const float rs  = rsqrtf(fmaxf(var, 0.0f) + EPS);
  const float s   = g[c] * rs;
  scsh[c]      = s;
  scsh[64 + c] = be[c] - mu * s;
}

extern "C" void kernel_launch(void* const* d_in, const int* in_sizes, int n_in,
                              void* d_out, int out_size, void* d_ws, size_t ws_size,
                              hipStream_t stream) {
  const int N = in_sizes[0] / 64;
  const int E = in_sizes[1] / 64;
  const float* x   = (const float*)d_in[0];
  const float* ea  = (const float*)d_in[1];
  // d_in[2] = u (unused by reference)
  const float* W1  = (const float*)d_in[3];
  const float* b1  = (const float*)d_in[4];
  const float* g1  = (const float*)d_in[5];
  const float* be1 = (const float*)d_in[6];
  const float* W2  = (const float*)d_in[7];
  const float* b2  = (const float*)d_in[8];
  const float* g2  = (const float*)d_in[9];
  const float* be2 = (const float*)d_in[10];
  const int* ei   = (const int*)d_in[11];  // [2,E] int32
  const int* row  = ei;
  const int* colv = ei + E;
  // d_in[12] = batch (unused by reference)

  float* sums  = (float*)d_ws;          // N*64
  float* cnt   = sums + (size_t)N * 64; // N
  float* statE = cnt + N;               // 128 (sum | sumsq)
  float* statN = statE + 128;           // 128
  float* scsh1 = statN + 128;           // 128 (scale | shift)
  float* scsh2 = scsh1 + 128;           // 128
  // total ws: (N*65 + 512) * 4 bytes ~= 26 MB

  hipMemsetAsync(d_ws, 0, ((size_t)N * 65 + 512) * sizeof(float), stream);

  const int ntE = (E + 63) / 64;
  const int ntN = (N + 63) / 64;
  const int gE  = ntE < 2048 ? ntE : 2048;
  const int gN  = ntN < 2048 ? ntN : 2048;

  fused_gemm<0><<<dim3(gE), dim3(256), 0, stream>>>(
      x, ea, nullptr, nullptr, row, nullptr, W1, b1, nullptr,
      statE, statE + 64, nullptr, nullptr, nullptr, E, ntE);
  finalize_stats<<<dim3(1), dim3(64), 0, stream>>>(statE, statE + 64, g1, be1, scsh1,
                                                   1.0f / (float)E);
  fused_gemm<1><<<dim3(gE), dim3(256), 0, stream>>>(
      x, ea, nullptr, nullptr, row, colv, W1, b1, scsh1,
      nullptr, nullptr, sums, cnt, nullptr, E, ntE);
  fused_gemm<2><<<dim3(gN), dim3(256), 0, stream>>>(
      x, nullptr, sums, cnt, nullptr, nullptr, W2, b2, nullptr,
      statN, statN + 64, nullptr, nullptr, nullptr, N, ntN);
  finalize_stats<<<dim3(1), dim3(64), 0, stream>>>(statN, statN + 64, g2, be2, scsh2,
                                                   1.0f / (float)N);
  fused_gemm<3><<<dim3(gN), dim3(256), 0, stream>>>(
      x, nullptr, sums, cnt, nullptr, nullptr, W2, b2, scsh2,
      nullptr, nullptr, nullptr, nullptr, (float*)d_out, N, ntN);
}